// Round 6
// baseline (2373.674 us; speedup 1.0000x reference)
//
#include <hip/hip_runtime.h>

typedef unsigned short u16;
typedef unsigned int u32;
typedef unsigned long long u64;
typedef __attribute__((ext_vector_type(8))) short short8;
typedef __attribute__((ext_vector_type(4))) float f32x4;

#define N_ELEM 8388608
#define NH 32
#define SEQ 2048
#define HD 128
#define KTOP 32768u
#define HIST_BASE 16384u   // bin for |x|=2.0 ; count(|x|>2.0)~382K >> 32768 (safe)
#define POOL_T0 16416u     // bin for |x|=2.5 ; count(|x|>2.5)~104K >> 32768 (safe)
#define POOL_CAP 131072u   // ~104K expected, 26% headroom
#define KSEL_CAP 6144u     // bin==t ties ~2400, 2.5x headroom

__device__ __forceinline__ u16 f2bf(float f) {
  union { float f; u32 u; } v; v.f = f;
  u32 r = v.u + 0x7fffu + ((v.u >> 16) & 1u);
  return (u16)(r >> 16);
}

// fp32 quant-dequant, exact reference semantics; keeps outliers & sinks verbatim
__device__ __forceinline__ float dqf(float x, u32 t, u64 Kr, u32 idx, bool sink, float scale) {
  union { float f; u32 u; } w; w.f = x;
  const u32 ab = w.u & 0x7fffffffu;
  const u32 bin = ab >> 16;
  const bool keep = sink || (bin > t) ||
                    (bin == t && ((((u64)ab) << 32) | (u32)(~idx)) >= Kr);
  if (keep) return x;
  float q = rintf(x / scale);            // round-half-even == jnp.round
  q = fminf(fmaxf(q, -8.0f), 7.0f);
  return q * scale;
}

// DPP 16-lane row reductions
template<int CTRL>
__device__ __forceinline__ float dppmov(float x) {
  union { float f; int i; } a, b;
  a.f = x;
  b.i = __builtin_amdgcn_mov_dpp(a.i, CTRL, 0xF, 0xF, true);
  return b.f;
}
__device__ __forceinline__ float rowmax16(float x) {
  x = fmaxf(x, dppmov<0xB1>(x));
  x = fmaxf(x, dppmov<0x4E>(x));
  x = fmaxf(x, dppmov<0x141>(x));
  x = fmaxf(x, dppmov<0x140>(x));
  return x;
}
__device__ __forceinline__ float rowsum16(float x) {
  x += dppmov<0xB1>(x);
  x += dppmov<0x4E>(x);
  x += dppmov<0x141>(x);
  x += dppmov<0x140>(x);
  return x;
}

// ---------------- K1: fused single pass: tail-hist + pool gather + col-max ----------
// grid (256,2): h = bx>>3, row-eighth = bx&7 (256 rows). Hist only bins>=HIST_BASE
// (|x|>=2.0, 4.6% of data); pool = all (ab,idx) with bin>=POOL_T0; colmax over rest.
__global__ __launch_bounds__(256) void scan_kernel(const float* __restrict__ k,
                                                   const float* __restrict__ v,
                                                   u32* __restrict__ ctrl,
                                                   u32* __restrict__ histK, u32* __restrict__ histV,
                                                   u32* __restrict__ paK, u32* __restrict__ piK,
                                                   u32* __restrict__ paV, u32* __restrict__ piV,
                                                   u32* __restrict__ kmax, u32* __restrict__ vmax) {
  __shared__ u32 sh[8192];     // 16384 packed u16 bins (rel to HIST_BASE)
  __shared__ u32 colmax[128];
  const int tensor = blockIdx.y;
  const float* src = tensor ? v : k;
  u32* gh = tensor ? histV : histK;
  u32* pa = tensor ? paV : paK;
  u32* pi = tensor ? piV : piK;
  u32* cnt = &ctrl[tensor * 8 + 4];
  u32* mbuf = tensor ? vmax : kmax;
  const int h = blockIdx.x >> 3, q8 = blockIdx.x & 7;
  const int tid = threadIdx.x;
  for (int i = tid; i < 8192; i += 256) sh[i] = 0;
  if (tid < 128) colmax[tid] = 0;
  __syncthreads();
  const int c0 = 4 * (tid & 31);
  u32 mx[4] = {0, 0, 0, 0};
  for (int p = 0; p < 32; ++p) {
    const int s = q8 * 256 + p * 8 + (tid >> 5);
    const u32 idx = ((u32)(h * SEQ + s) << 7) + (u32)c0;
    f32x4 x = *(const f32x4*)(src + idx);
    const bool skipmax = (tensor == 1 && s < 4);
#pragma unroll
    for (int j = 0; j < 4; ++j) {
      union { float f; u32 u; } w; w.f = x[j];
      const u32 ab = w.u & 0x7fffffffu;
      const u32 bin = ab >> 16;
      if (bin >= HIST_BASE) {
        const u32 rel = bin - HIST_BASE;
        atomicAdd(&sh[rel >> 1], 1u << ((rel & 1u) * 16));
      }
      if (bin >= POOL_T0) {
        u32 slot = atomicAdd(cnt, 1u);
        if (slot < POOL_CAP) { pa[slot] = ab; pi[slot] = idx + j; }
      } else if (!skipmax && ab > mx[j]) mx[j] = ab;
    }
  }
#pragma unroll
  for (int j = 0; j < 4; ++j) atomicMax(&colmax[c0 + j], mx[j]);
  __syncthreads();
  if (tid < 128) atomicMax(&mbuf[h * HD + tid], colmax[tid]);
  // sparse flush of tail hist
  for (int i = tid; i < 8192; i += 256) {
    u32 w = sh[i];
    u32 lo = w & 0xffffu, hi = w >> 16;
    if (lo) atomicAdd(&gh[2 * i], lo);
    if (hi) atomicAdd(&gh[2 * i + 1], hi);
  }
}

// ---------------- K2: threshold bin t + tie budget r (16384-bin tail hist) ----------
// ctrl per tensor (8 u32): [t, r, KrHi, KrLo, poolCount, -, -, -]
__global__ __launch_bounds__(256) void thresh_kernel(const u32* __restrict__ histK,
                                                     const u32* __restrict__ histV,
                                                     u32* __restrict__ ctrl) {
  const u32* hist = blockIdx.x ? histV : histK;
  u32* c = ctrl + blockIdx.x * 8;
  __shared__ u32 part[256];
  __shared__ u32 bins[64];
  __shared__ u32 sh_chunk, sh_cum;
  u32 s = 0;
  for (int i = 0; i < 64; ++i) s += hist[threadIdx.x * 64 + i];
  part[threadIdx.x] = s;
  __syncthreads();
  if (threadIdx.x == 0) {
    u32 cum = 0;
    int chunk = 255;
    while (chunk > 0 && cum + part[chunk] < KTOP) { cum += part[chunk]; --chunk; }
    sh_chunk = (u32)chunk; sh_cum = cum;
  }
  __syncthreads();
  const u32 chunk = sh_chunk;
  if (threadIdx.x < 64) bins[threadIdx.x] = hist[chunk * 64 + threadIdx.x];
  __syncthreads();
  if (threadIdx.x == 0) {
    u32 cum = sh_cum;
    int b = 63;
    while (b > 0 && cum + bins[b] < KTOP) { cum += bins[b]; --b; }
    c[0] = HIST_BASE + chunk * 64 + (u32)b;   // absolute threshold bin
    c[1] = KTOP - cum;                        // r ties to take
  }
}

// ---------------- K3: Kr = r-th largest key among bin==t pool entries ---------------
__global__ __launch_bounds__(256) void ksel_kernel(u32* __restrict__ ctrl,
                                                   const u32* __restrict__ paK, const u32* __restrict__ piK,
                                                   const u32* __restrict__ paV, const u32* __restrict__ piV) {
  __shared__ u64 keys[KSEL_CAP];
  __shared__ u32 kcnt;
  const int tensor = blockIdx.y;
  u32* c = ctrl + tensor * 8;
  const u32 t = c[0], r = c[1];
  u32 P = c[4]; if (P > POOL_CAP) P = POOL_CAP;
  const u32* pa = tensor ? paV : paK;
  const u32* pi = tensor ? piV : piK;
  if (threadIdx.x == 0) kcnt = 0;
  __syncthreads();
  for (u32 i = threadIdx.x; i < P; i += 256) {
    const u32 ab = pa[i];
    if ((ab >> 16) == t) {
      u32 slot = atomicAdd(&kcnt, 1u);
      if (slot < KSEL_CAP) keys[slot] = (((u64)ab) << 32) | (u32)(~pi[i]);
    }
  }
  __syncthreads();
  u32 T = kcnt; if (T > KSEL_CAP) T = KSEL_CAP;
  for (u32 i = blockIdx.x * 256 + threadIdx.x; i < T; i += 32 * 256) {
    const u64 ki = keys[i];
    u32 cnt2 = 0;
    for (u32 j = 0; j < T; ++j) cnt2 += (keys[j] > ki) ? 1u : 0u;
    if (cnt2 == r - 1) { c[2] = (u32)(ki >> 32); c[3] = (u32)ki; }
  }
}

// ---------------- K4: fold pool non-outliers into col max + compute scales ----------
__global__ __launch_bounds__(256) void maxfix_scale_kernel(const u32* __restrict__ ctrl,
                                                           const u32* __restrict__ paK, const u32* __restrict__ piK,
                                                           const u32* __restrict__ paV, const u32* __restrict__ piV,
                                                           u32* __restrict__ kmax, u32* __restrict__ vmax,
                                                           float* __restrict__ kscale, float* __restrict__ vscale) {
  const int tensor = blockIdx.x;
  const u32* c = ctrl + tensor * 8;
  const u32 t = c[0];
  const u64 Kr = (((u64)c[2]) << 32) | c[3];
  u32 P = c[4]; if (P > POOL_CAP) P = POOL_CAP;
  const u32* pa = tensor ? paV : paK;
  const u32* pi = tensor ? piV : piK;
  u32* mbuf = tensor ? vmax : kmax;
  for (u32 i = threadIdx.x; i < P; i += 256) {
    const u32 ab = pa[i], idx = pi[i];
    const u32 bin = ab >> 16;
    if (bin > t) continue;                                 // outlier
    if (bin == t && ((((u64)ab) << 32) | (u32)(~idx)) >= Kr) continue;  // outlier
    if (tensor == 1 && ((idx >> 7) & 2047) < 4) continue;  // V sink: excluded from scale
    atomicMax(&mbuf[(idx >> 18) * HD + (idx & 127)], ab);
  }
  __syncthreads();
  float* sbuf = tensor ? vscale : kscale;
  for (int i = threadIdx.x; i < NH * HD; i += 256) {
    union { u32 u; float f; } a; a.u = mbuf[i];
    sbuf[i] = fmaxf(a.f, 1e-6f) / 7.0f;
  }
}

// ---------------- K5: unified reconstruct: z=0 -> krec row-major, z=1 -> vrecT tiles
__global__ __launch_bounds__(256) void recon_kernel(const float* __restrict__ K,
                                                    const float* __restrict__ V,
                                                    const u32* __restrict__ ctrl,
                                                    const float* __restrict__ kscale,
                                                    const float* __restrict__ vscale,
                                                    u16* __restrict__ krec,
                                                    u16* __restrict__ vrecT) {
  __shared__ u32 ld[64][65];
  const int tid = threadIdx.x;
  if (blockIdx.y == 0) {
    // K: 1024 blocks x 8192 elems
    const u32 t = ctrl[0];
    const u64 Kr = (((u64)ctrl[2]) << 32) | ctrl[3];
    const u32 base = blockIdx.x * 8192;
#pragma unroll
    for (int i = 0; i < 8; ++i) {
      const u32 e = base + (u32)(i * 256 + tid) * 4;
      const u32 d0 = e & 127, h = e >> 18;
      f32x4 x = *(const f32x4*)(K + e);
      f32x4 sc = *(const f32x4*)(kscale + h * HD + d0);
      u16 y[4];
#pragma unroll
      for (int j = 0; j < 4; ++j) y[j] = f2bf(dqf(x[j], t, Kr, e + j, false, sc[j]));
      *(u32*)(krec + e) = ((u32)y[0]) | (((u32)y[1]) << 16);
      *(u32*)(krec + e + 2) = ((u32)y[2]) | (((u32)y[3]) << 16);
    }
  } else {
    // V: 1024 blocks = (h=bx>>5, sb=bx&31): 128ch x 64tok transposed tile
    const u32 t = ctrl[8];
    const u64 Kr = (((u64)ctrl[10]) << 32) | ctrl[11];
    const int h = blockIdx.x >> 5, sb = blockIdx.x & 31;
    const int d0 = 4 * (tid & 31);
    f32x4 sc = *(const f32x4*)(vscale + h * HD + d0);
#pragma unroll
    for (int p = 0; p < 8; ++p) {
      const int sl = p * 8 + (tid >> 5);
      const int tok = sb * 64 + sl;
      const bool sink = tok < 4;
      const u32 idx = ((u32)(h * SEQ + tok) << 7) + (u32)d0;
      f32x4 x = *(const f32x4*)(V + idx);
      u16 y[4];
#pragma unroll
      for (int j = 0; j < 4; ++j) y[j] = f2bf(dqf(x[j], t, Kr, idx + j, sink, sc[j]));
      ld[(d0 >> 1)][sl] = ((u32)y[0]) | (((u32)y[1]) << 16);
      ld[(d0 >> 1) + 1][sl] = ((u32)y[2]) | (((u32)y[3]) << 16);
    }
    __syncthreads();
    const int d = tid >> 1, so = (tid & 1) * 32, e = d & 1;
    u16* outp = vrecT + (size_t)(h * 32 + sb) * 8192 + d * 64 + so;
#pragma unroll
    for (int i = 0; i < 4; ++i) {
      short8 y;
#pragma unroll
      for (int m = 0; m < 8; ++m) {
        const u32 w2 = ld[d >> 1][so + i * 8 + m];
        y[m] = (short)(u16)(w2 >> (16 * e));
      }
      *(short8*)(outp + i * 8) = y;
    }
  }
}

// ---------------- K6: flash attention, paired q-tiles, shared B-frag reads ----------
__global__ __launch_bounds__(256, 2) void flash_pre(const float* __restrict__ Q,
                                                    const u16* __restrict__ krec,
                                                    const u16* __restrict__ vrecT,
                                                    float* __restrict__ Out) {
  __shared__ u16 ks[64][136];       // K tile (token x channel), pad 128->136
  __shared__ u16 vt[128][72];       // V^T tile (channel x token), pad 64->72
  __shared__ u16 pl[4][2][16][72];  // per-wave per-subtile P tile

  const int blk = blockIdx.x;       // 512 = 32 heads x 16 pairs
  const int h = blk >> 4;
  const int pa = blk & 15;
  const int RA = pa << 6;           // subtile 0 rows
  const int RB = (31 - pa) << 6;    // subtile 1 rows
  const int tid = threadIdx.x;
  const int w = tid >> 6, lane = tid & 63;
  const int l16 = lane & 15, quad = lane >> 4;
  const float SC = 0.12751743f;     // log2(e)/sqrt(128)
  const float NEG = -30000.0f;

  short8 qf[2][4];
#pragma unroll
  for (int m = 0; m < 2; ++m) {
    const int R = m ? RB : RA;
    const float* qp = Q + ((size_t)(h * SEQ + R + w * 16 + l16)) * HD + quad * 8;
#pragma unroll
    for (int c = 0; c < 4; ++c) {
      f32x4 a = *(const f32x4*)(qp + c * 32);
      f32x4 b = *(const f32x4*)(qp + c * 32 + 4);
#pragma unroll
      for (int j = 0; j < 4; ++j) {
        qf[m][c][j] = (short)f2bf(a[j]);
        qf[m][c][4 + j] = (short)f2bf(b[j]);
      }
    }
  }

  f32x4 o[2][8];
  float mrow[2][4], lrow[2][4];
#pragma unroll
  for (int m = 0; m < 2; ++m) {
#pragma unroll
    for (int i = 0; i < 8; ++i) o[m][i] = (f32x4){0.f, 0.f, 0.f, 0.f};
#pragma unroll
    for (int r = 0; r < 4; ++r) { mrow[m][r] = NEG; lrow[m][r] = 0.f; }
  }

  const int krow = tid >> 2, kqo = (tid & 3) * 32;
  const int vd = tid >> 1, vso = (tid & 1) * 32;
  const u16* kbase = krec + ((size_t)h * SEQ + krow) * HD + kqo;
  const u16* vbase = vrecT + (size_t)h * 32 * 8192 + vd * 64 + vso;
  short8 kr[4], vr[4];
#pragma unroll
  for (int i = 0; i < 4; ++i) kr[i] = *(const short8*)(kbase + i * 8);
#pragma unroll
  for (int i = 0; i < 4; ++i) vr[i] = *(const short8*)(vbase + i * 8);

  const int ktiles = (RB >> 6) + 1;
  for (int kt = 0; kt < ktiles; ++kt) {
    const int kb = kt << 6;
    __syncthreads();
#pragma unroll
    for (int i = 0; i < 4; ++i) *(short8*)(&ks[krow][kqo + i * 8]) = kr[i];
#pragma unroll
    for (int i = 0; i < 4; ++i) *(short8*)(&vt[vd][vso + i * 8]) = vr[i];
    __syncthreads();
    if (kt + 1 < ktiles) {
      const u16* kp = kbase + (size_t)(kt + 1) * 64 * HD;
      const u16* vp = vbase + (size_t)(kt + 1) * 8192;
#pragma unroll
      for (int i = 0; i < 4; ++i) kr[i] = *(const short8*)(kp + i * 8);
#pragma unroll
      for (int i = 0; i < 4; ++i) vr[i] = *(const short8*)(vp + i * 8);
    }
    const bool act0 = (kb <= RA);   // subtile 0 still in range (block-uniform)

    // S = Q K^T for both subtiles, kf read ONCE
    f32x4 sa[2][4];
#pragma unroll
    for (int ni = 0; ni < 4; ++ni) {
      f32x4 a0 = (f32x4){0.f, 0.f, 0.f, 0.f};
      f32x4 a1 = a0;
#pragma unroll
      for (int c = 0; c < 4; ++c) {
        short8 kf = *(const short8*)(&ks[ni * 16 + l16][c * 32 + quad * 8]);
        if (act0) a0 = __builtin_amdgcn_mfma_f32_16x16x32_bf16(qf[0][c], kf, a0, 0, 0, 0);
        a1 = __builtin_amdgcn_mfma_f32_16x16x32_bf16(qf[1][c], kf, a1, 0, 0, 0);
      }
      sa[0][ni] = a0; sa[1][ni] = a1;
    }

    // mask + online softmax + P->LDS + O rescale per active subtile
#pragma unroll
    for (int m = 0; m < 2; ++m) {
      if (m == 0 && !act0) continue;
      const int R = m ? RB : RA;
      const bool diag = (kb == R);
#pragma unroll
      for (int ni = 0; ni < 4; ++ni)
#pragma unroll
        for (int r = 0; r < 4; ++r) {
          float sv = sa[m][ni][r] * SC;
          if (diag && (ni * 16 + l16) > (w * 16 + quad * 4 + r)) sv = NEG;
          sa[m][ni][r] = sv;
        }
      float alpha[4];
#pragma unroll
      for (int r = 0; r < 4; ++r) {
        float mx = fmaxf(fmaxf(sa[m][0][r], sa[m][1][r]), fmaxf(sa[m][2][r], sa[m][3][r]));
        mx = rowmax16(mx);
        const float mn = fmaxf(mrow[m][r], mx);
        alpha[r] = exp2f(mrow[m][r] - mn);
        mrow[m][r] = mn;
        float sum = 0.f;
#pragma unroll
        for (int ni = 0; ni < 4; ++ni) {
          const float p = exp2f(sa[m][ni][r] - mn);
          sa[m][ni][r] = p;
          sum += p;
        }
        sum = rowsum16(sum);
        lrow[m][r] = lrow[m][r] * alpha[r] + sum;
      }
#pragma unroll
      for (int ni = 0; ni < 4; ++ni)
#pragma unroll
        for (int r = 0; r < 4; ++r)
          pl[w][m][quad * 4 + r][ni * 16 + l16] = f2bf(sa[m][ni][r]);
#pragma unroll
      for (int i = 0; i < 8; ++i)
#pragma unroll
        for (int r = 0; r < 4; ++r) o[m][i][r] *= alpha[r];
    }

    // O += P V, vf read ONCE for both subtiles
#pragma unroll
    for (int kc = 0; kc < 2; ++kc) {
      short8 af0 = *(const short8*)(&pl[w][0][l16][kc * 32 + quad * 8]);
      short8 af1 = *(const short8*)(&pl[w][1][l16][kc * 32 + quad * 8]);
#pragma unroll
      for (int ds = 0; ds < 8; ++ds) {
        short8 vf = *(const short8*)(&vt[ds * 16 + l16][kc * 32 + quad * 8]);
        if (act0) o[0][ds] = __builtin_amdgcn_mfma_f32_16x16x32_bf16(af0, vf, o[0][ds], 0, 0, 0);
        o[1][ds] = __builtin_amdgcn_mfma_f32_16x16x32_bf16(af1, vf, o[1][ds], 0, 0, 0);
      }
    }
  }
#pragma unroll
  for (int m = 0; m < 2; ++m) {
    const int R = m ? RB : RA;
#pragma unroll
    for (int r = 0; r < 4; ++r) {
      const float inv = 1.0f / lrow[m][r];
      const int qr = R + w * 16 + quad * 4 + r;
      float* op = Out + ((size_t)(h * SEQ + qr)) * HD + l16;
#pragma unroll
      for (int ds = 0; ds < 8; ++ds) op[ds * 16] = o[m][ds][r] * inv;
    }
  }
}

// ---------------- fallback flash (inline dequant, small-ws path) ----------
__global__ __launch_bounds__(256, 2) void flash_fb(const float* __restrict__ Q,
                                                   const float* __restrict__ K,
                                                   const float* __restrict__ V,
                                                   const u32* __restrict__ ctrl,
                                                   const float* __restrict__ kscale,
                                                   const float* __restrict__ vscale,
                                                   float* __restrict__ Out) {
  __shared__ u16 ks[64][136];
  __shared__ u16 vt[128][72];
  __shared__ u16 pl[4][16][72];
  const int blk = blockIdx.x;
  const int h = blk >> 5;
  const int qt = 31 - (blk & 31);
  const int qb = qt << 6;
  const int tid = threadIdx.x;
  const int w = tid >> 6, lane = tid & 63;
  const int l16 = lane & 15, quad = lane >> 4;
  const float SM_SCALE = 0.08838834764831843f;
  const float NEG = -30000.0f;
  const u32 tK = ctrl[0];
  const u64 KrK = (((u64)ctrl[2]) << 32) | ctrl[3];
  const u32 tV = ctrl[8];
  const u64 KrV = (((u64)ctrl[10]) << 32) | ctrl[11];
  const int cch = (tid & 15) * 8;
  float ksc[8], vsc[8];
#pragma unroll
  for (int j = 0; j < 8; ++j) {
    ksc[j] = kscale[h * HD + cch + j];
    vsc[j] = vscale[h * HD + cch + j];
  }
  short8 qf[4];
  {
    const float* qp = Q + ((size_t)(h * SEQ + qb + w * 16 + l16)) * HD + quad * 8;
#pragma unroll
    for (int c = 0; c < 4; ++c) {
      f32x4 a = *(const f32x4*)(qp + c * 32);
      f32x4 b = *(const f32x4*)(qp + c * 32 + 4);
#pragma unroll
      for (int j = 0; j < 4; ++j) {
        qf[c][j] = (short)f2bf(a[j]);
        qf[c][4 + j] = (short)f2bf(b[j]);
      }
    }
  }
  f32x4 o[8];
#pragma unroll
  for (int i = 0; i < 8; ++i) o[i] = (f32x4){0.f, 0.f, 0.f, 0.f};
  float mrow[4], lrow[4];
#pragma unroll
  for (int r = 0; r < 4; ++r) { mrow[r] = NEG; lrow[r] = 0.f; }
  const int ktiles = qt + 1;
  for (int kt = 0; kt < ktiles; ++kt) {
    const int kb = kt << 6;
    __syncthreads();
    {
      const int r0 = tid >> 4;
      const float* kp = K + (size_t)(h * SEQ + kb) * HD;
#pragma unroll
      for (int i = 0; i < 4; ++i) {
        const int row = r0 + i * 16;
        f32x4 x0 = *(const f32x4*)(kp + (size_t)row * HD + cch);
        f32x4 x1 = *(const f32x4*)(kp + (size_t)row * HD + cch + 4);
        const u32 bidx = ((u32)(h * SEQ + kb + row) << 7) + (u32)cch;
        short8 yv;
#pragma unroll
        for (int j = 0; j < 4; ++j) {
          yv[j]     = (short)f2bf(dqf(x0[j], tK, KrK, bidx + j,     false, ksc[j]));
          yv[4 + j] = (short)f2bf(dqf(x1[j], tK, KrK, bidx + 4 + j, false, ksc[4 + j]));
        }
        *(short8*)(&ks[row][cch]) = yv;
      }
    }
    {
      const float* vp = V + (size_t)(h * SEQ + kb) * HD;
#pragma unroll
      for (int i = 0; i < 4; ++i) {
        const int tchunk = tid + i * 256;
        const int s = tchunk >> 4;
        const int tok = kb + s;
        const bool sink = tok < 4;
        f32x4 x0 = *(const f32x4*)(vp + (size_t)s * HD + cch);
        f32x4 x1 = *(const f32x4*)(vp + (size_t)s * HD + cch + 4);
        const u32 bidx = ((u32)(h * SEQ + tok) << 7) + (u32)cch;
#pragma unroll
        for (int j = 0; j < 4; ++j) {
          vt[cch + j][s]     = f2bf(dqf(x0[j], tV, KrV, bidx + j,     sink, vsc[j]));
          vt[cch + 4 + j][s] = f2bf(dqf(x1[j], tV, KrV, bidx + 4 + j, sink, vsc[4 + j]));
        }
      }
    }
    __syncthreads();
    f32x4 sa[4];
#pragma unroll
    for (int ni = 0; ni < 4; ++ni) {
      f32x4 acc = (f32x4){0.f, 0.f, 0.f, 0.f};
#pragma unroll
      for (int c = 0; c < 4; ++c) {
        short8 kf = *(const short8*)(&ks[ni * 16 + l16][c * 32 + quad * 8]);
        acc = __builtin_amdgcn_mfma_f32_16x16x32_bf16(qf[c], kf, acc, 0, 0, 0);
      }
      sa[ni] = acc;
    }
    const bool diag = (kb == qb);
#pragma unroll
    for (int ni = 0; ni < 4; ++ni)
#pragma unroll
      for (int r = 0; r < 4; ++r) {
        float sv = sa[ni][r] * SM_SCALE;
        if (diag) {
          const int qr = w * 16 + quad * 4 + r;
          const int kc = ni * 16 + l16;
          if (kc > qr) sv = NEG;
        }
        sa[ni][r] = sv;
      }
    float alpha[4];
#pragma unroll
    for (int r = 0; r < 4; ++r) {
      float mx = fmaxf(fmaxf(sa[0][r], sa[1][r]), fmaxf(sa[2][r], sa[3][r]));
      mx = fmaxf(mx, __shfl_xor(mx, 1));
      mx = fmaxf(mx, __shfl_xor(mx, 2));
      mx = fmaxf(mx, __shfl_xor(mx, 4));
      mx = fmaxf(mx, __shfl_xor(mx, 8));
      const float mn = fmaxf(mrow[r], mx);
      alpha[r] = __expf(mrow[r] - mn);
      mrow[r] = mn;
      float sum = 0.f;
#pragma unroll
      for (int ni = 0; ni < 4; ++ni) {
        const float p = __expf(sa[ni][r] - mn);
        sa[ni][r] = p;
        sum += p;
      }
      sum += __shfl_xor(sum, 1);
      sum += __shfl_xor(sum, 2);
      sum += __shfl_xor(sum, 4);
      sum += __shfl_xor(sum, 8);
      lrow[r] = lrow[r] * alpha[r] + sum;
    }
#pragma unroll
    for (int ni = 0; ni < 4; ++ni)
#pragma unroll
      for (int r = 0; r < 4; ++r)
        pl[w][quad * 4 + r][ni * 16 + l16] = f2bf(sa[ni][r]);
    __syncthreads();
#pragma unroll
    for (int i = 0; i < 8; ++i)
#pragma unroll
      for (int r = 0; r < 4; ++r) o[i][r] *= alpha[r];
#pragma unroll
    for (int kc = 0; kc < 2; ++kc) {
      short8 af = *(const short8*)(&pl[w][l16][kc * 32 + quad * 8]);
#pragma unroll
      for (int ds = 0; ds < 8; ++ds) {
        short8 vf = *(const short8*)(&vt[ds * 16 + l16][kc * 32 + quad * 8]);
        o[ds] = __builtin_amdgcn_mfma_f32_16x16x32_bf16(af, vf, o[ds], 0, 0, 0);
      }
    }
  }
#pragma unroll
  for (int r = 0; r < 4; ++r) {
    const float inv = 1.0f / lrow[r];
    const int qr = qb + w * 16 + quad * 4 + r;
    float* op = Out + ((size_t)(h * SEQ + qr)) * HD + l16;
#pragma unroll
    for (int ds = 0; ds < 8; ++ds) op[ds * 16] = o[ds][r] * inv;
  }
}

// ---------------- launcher ----------------
extern "C" void kernel_launch(void* const* d_in, const int* in_sizes, int n_in,
                              void* d_out, int out_size, void* d_ws, size_t ws_size,
                              hipStream_t stream) {
  const float* q = (const float*)d_in[0];
  const float* k = (const float*)d_in[1];
  const float* v = (const float*)d_in[2];
  float* out = (float*)d_out;
  char* ws = (char*)d_ws;

  u32* ctrl    = (u32*)ws;                        // 256 B
  u32* histK   = (u32*)(ws + 256);                // 64 KB (tail bins 16384..32767)
  u32* histV   = (u32*)(ws + 65792);              // 64 KB
  u32* kmax    = (u32*)(ws + 131328);             // 16 KB
  u32* vmax    = (u32*)(ws + 147712);             // 16 KB
  const size_t ZERO_BYTES = 164096;
  float* kscale = (float*)(ws + 164096);          // 16 KB
  float* vscale = (float*)(ws + 180480);          // 16 KB
  // pools overlaid on krec region (pools dead before recon writes krec)
  u32* paK = (u32*)(ws + 196864);                 // 512 KB
  u32* piK = paK + POOL_CAP;                      // 512 KB
  u32* paV = piK + POOL_CAP;                      // 512 KB
  u32* piV = paV + POOL_CAP;                      // 512 KB
  u16* krec  = (u16*)(ws + 196864);               // 16 MB (overlays pools)
  u16* vrecT = (u16*)(ws + 196864 + 16777216);    // 16 MB
  const size_t NEED = 196864 + 2ull * 16777216;   // 33751296 (< round-5's proven 34 MB)

  hipMemsetAsync(ws, 0, ZERO_BYTES, stream);
  scan_kernel<<<dim3(256, 2), 256, 0, stream>>>(k, v, ctrl, histK, histV,
                                                paK, piK, paV, piV, kmax, vmax);
  thresh_kernel<<<2, 256, 0, stream>>>(histK, histV, ctrl);
  ksel_kernel<<<dim3(32, 2), 256, 0, stream>>>(ctrl, paK, piK, paV, piV);
  maxfix_scale_kernel<<<2, 256, 0, stream>>>(ctrl, paK, piK, paV, piV,
                                             kmax, vmax, kscale, vscale);
  if (ws_size >= NEED) {
    recon_kernel<<<dim3(1024, 2), 256, 0, stream>>>(k, v, ctrl, kscale, vscale, krec, vrecT);
    flash_pre<<<512, 256, 0, stream>>>(q, krec, vrecT, out);
  } else {
    flash_fb<<<32 * 32, 256, 0, stream>>>(q, k, v, ctrl, kscale, vscale, out);
  }
}